// Round 6
// baseline (286.993 us; speedup 1.0000x reference)
//
#include <hip/hip_runtime.h>
#include <cstdint>
#include <cstddef>

#define NH 8
#define LQ 2048
#define DH 64
#define NKT_HALF 16   // split-k: each block does 16 of the 32 k-tiles

typedef __attribute__((ext_vector_type(8))) __bf16 bf16x8;
typedef __attribute__((ext_vector_type(8))) unsigned short ushort8;
typedef __attribute__((ext_vector_type(4))) float floatx4;

__device__ __forceinline__ unsigned short bf_trunc(float x) {
    return (unsigned short)(__float_as_uint(x) >> 16);
}
__device__ __forceinline__ float bf_up(unsigned short h) {
    return __uint_as_float(((unsigned int)h) << 16);
}
__device__ __forceinline__ unsigned short bf_rne(float x) {
    unsigned int u = __float_as_uint(x);
    return (unsigned short)((u + 0x7FFFu + ((u >> 16) & 1u)) >> 16);
}
struct hl_t { unsigned short h, l; };
// x ~= h + l with |x-h-l| <= 2^-16 |x|
__device__ __forceinline__ hl_t split2(float x) {
    hl_t r;
    r.h = bf_trunc(x);
    r.l = bf_trunc(x - bf_up(r.h));
    return r;
}

#define MFMA16(A, B, C) __builtin_amdgcn_mfma_f32_16x16x32_bf16((A), (B), (C), 0, 0, 0)

// ---------------------------------------------------------------------------
// prep_kernel: one-shot conversion pass (proven R4). K pre-scaled 0.125,
// V pre-transposed + c-folded, meta pre-folded. Hot loop stages pure copies.
// ---------------------------------------------------------------------------
__global__ __launch_bounds__(256) void prep_kernel(
    const float* __restrict__ kp,  const float* __restrict__ vp,
    const float* __restrict__ cp,  const float* __restrict__ dktp,
    const float* __restrict__ dkbp,const float* __restrict__ dksp,
    const float* __restrict__ Wwp, const float* __restrict__ Wbp,
    unsigned short* __restrict__ khig, unsigned short* __restrict__ klog,
    unsigned short* __restrict__ vhig, unsigned short* __restrict__ vlog,
    float* __restrict__ metag)
{
    const int bid = blockIdx.x;
    const int t   = threadIdx.x;

    if (bid < 256) {
        const int h = bid >> 5, kt = bid & 31;
        const int row = t >> 2, s = t & 3;
        const size_t kg = (size_t)(h * LQ) + kt * 64 + row;
        const float* src = kp + kg * DH + s * 16;
        unsigned short* dh_ = khig + kg * DH + s * 16;
        unsigned short* dl_ = klog + kg * DH + s * 16;
        ushort8 vh0, vh1, vl0, vl1;
#pragma unroll
        for (int j = 0; j < 2; ++j) {
            float4 x = *(const float4*)(src + 4 * j);
            hl_t a = split2(x.x * 0.125f), b = split2(x.y * 0.125f);
            hl_t c = split2(x.z * 0.125f), d = split2(x.w * 0.125f);
            vh0[4*j+0]=a.h; vl0[4*j+0]=a.l; vh0[4*j+1]=b.h; vl0[4*j+1]=b.l;
            vh0[4*j+2]=c.h; vl0[4*j+2]=c.l; vh0[4*j+3]=d.h; vl0[4*j+3]=d.l;
        }
#pragma unroll
        for (int j = 0; j < 2; ++j) {
            float4 x = *(const float4*)(src + 8 + 4 * j);
            hl_t a = split2(x.x * 0.125f), b = split2(x.y * 0.125f);
            hl_t c = split2(x.z * 0.125f), d = split2(x.w * 0.125f);
            vh1[4*j+0]=a.h; vl1[4*j+0]=a.l; vh1[4*j+1]=b.h; vl1[4*j+1]=b.l;
            vh1[4*j+2]=c.h; vl1[4*j+2]=c.l; vh1[4*j+3]=d.h; vl1[4*j+3]=d.l;
        }
        *(ushort8*)&dh_[0] = vh0; *(ushort8*)&dh_[8] = vh1;
        *(ushort8*)&dl_[0] = vl0; *(ushort8*)&dl_[8] = vl1;
    } else if (bid < 512) {
        const int h = (bid - 256) >> 5, kt = (bid - 256) & 31;
        const int p = t >> 4, mm = t & 15;
        const int k0 = kt * 64;
#pragma unroll
        for (int g = 0; g < 2; ++g) {
            const int kka = 2 * p + 32 * g;
            const float ca = cp[k0 + kka], cb = cp[k0 + kka + 1];
            const float* va = vp + ((size_t)(h * LQ + k0 + kka)) * DH;
            const float* vb = va + DH;
#pragma unroll
            for (int dd = 0; dd < 4; ++dd) {
                const int d = mm + 16 * dd;
                hl_t xa = split2(va[d] * ca);
                hl_t xb = split2(vb[d] * cb);
                const size_t base = ((size_t)(h * 32 + kt) * 64 + d) * 64 + kka;
                *(unsigned int*)&vhig[base] = (unsigned int)xa.h | ((unsigned int)xb.h << 16);
                *(unsigned int*)&vlog[base] = (unsigned int)xa.l | ((unsigned int)xb.l << 16);
            }
        }
    } else {
        const int idx = (bid - 512) * 256 + t;    // 0..16383
        const int h  = idx >> 11;
        const int kg = idx & 2047;
        float Ww[4], Wb[4];
#pragma unroll
        for (int f = 0; f < 4; ++f) { Ww[f] = Wwp[f * NH + h]; Wb[f] = Wbp[f * NH + h]; }
        const float* sc_ = dksp + (size_t)kg * 8;   // [2][4] top then bottom
        const float* tp  = dktp + (size_t)kg * 3;
        const float* bt  = dkbp + (size_t)kg * 3;
        float* mo = metag + ((size_t)(h * LQ) + kg) * 12;
        float cw = 0.f, cb2 = 0.f;
#pragma unroll
        for (int f = 0; f < 3; ++f) {
            const float stf = sc_[f], sbf = sc_[4 + f];
            const float A  = stf + sbf;
            const float Bv = tp[f] * stf + bt[f] * sbf;
            mo[f]     = A * Ww[f];
            mo[4 + f] = A * Wb[f];
            cw  -= Bv * Ww[f];
            cb2 -= Bv * Wb[f];
        }
        mo[3]  = cw;              mo[7]  = cb2;
        mo[8]  = sc_[3] * Ww[3];  mo[9]  = sc_[7] * Ww[3];
        mo[10] = sc_[3] * Wb[3];  mo[11] = sc_[7] * Wb[3];
    }
}

// ---------------------------------------------------------------------------
// attn_main. Grid: 512 = 32 qt * 8 h * 2 half. Block: 256 thr (4 waves).
// T14 async staging on BOTH streams:
//  - K/V/meta tile t+1 global->reg after B1 of tile t, reg->LDS at next top.
//  - rel features (rt/rb) tile t+1 -> second reg set, copied after PV.
// Dedicated sh_ebf for the P tile: removes the old B2 barrier (2 barriers/tile),
// and lets fast waves run epilogue/PV while slow waves finish QK.
// __launch_bounds__(256,2): grid gives 2 blocks/CU (8 waves/CU); VGPR cap 256.
// ---------------------------------------------------------------------------
__global__ __launch_bounds__(256, 2) void attn_main(
    const float* __restrict__ qp,  const float* __restrict__ dqp,
    const float* __restrict__ rtp, const float* __restrict__ rbp,
    const unsigned short* __restrict__ khig, const unsigned short* __restrict__ klog,
    const unsigned short* __restrict__ vhig, const unsigned short* __restrict__ vlog,
    const float* __restrict__ metag,
    float* __restrict__ probp, float* __restrict__ lws, float* __restrict__ pvws)
{
    __shared__ unsigned short sh_khi[64 * 72];   // Q-hi staging, then K-hi
    __shared__ unsigned short sh_klo[64 * 72];   // Q-lo staging, then K-lo
    __shared__ unsigned short sh_vhi[64 * 72];   // V^T hi (c folded in)
    __shared__ unsigned short sh_vlo[64 * 72];   // V^T lo
    __shared__ unsigned short sh_ebf[64 * 72];   // P tile bf16 (own-wave rows)
    __shared__ float sh_meta[64 * 12];
    __shared__ float sh_dqs[64 * 3];

    const int bid  = blockIdx.x;
    const int half = bid & 1;
    const int h    = (bid >> 1) & 7;
    const int qt   = bid >> 4;
    const int q0   = qt * 64;
    const int t    = threadIdx.x;
    const int lane = t & 63;
    const int m    = lane & 15;
    const int quad = lane >> 4;
    const int w16  = (t >> 6) * 16;

    // staging thread mapping (constant for whole kernel)
    const int srow = t >> 2, ss = t & 3;
    const int sbase = srow * 72 + ss * 16;
    const int mk = t / 3, mj = t - mk * 3;            // meta mapping, valid t<192

    // global cursors for tile 0 of this half
    size_t kgb = ((size_t)(h * LQ) + half * NKT_HALF * 64 + srow) * DH + ss * 16;
    size_t vgb = ((size_t)(h * 32 + half * NKT_HALF) * 64 + srow) * 64 + ss * 16;
    size_t mgb = ((size_t)(h * LQ) + half * NKT_HALF * 64 + mk) * 12 + mj * 4;

    // ---- issue tile-0 staged loads immediately (hide under Q prologue) ----
    ushort8 rkh0 = *(const ushort8*)&khig[kgb];
    ushort8 rkh1 = *(const ushort8*)&khig[kgb + 8];
    ushort8 rkl0 = *(const ushort8*)&klog[kgb];
    ushort8 rkl1 = *(const ushort8*)&klog[kgb + 8];
    ushort8 rvh0 = *(const ushort8*)&vhig[vgb];
    ushort8 rvh1 = *(const ushort8*)&vhig[vgb + 8];
    ushort8 rvl0 = *(const ushort8*)&vlog[vgb];
    ushort8 rvl1 = *(const ushort8*)&vlog[vgb + 8];
    float4  rmeta;
    if (t < 192) rmeta = *(const float4*)&metag[mgb];

    // ---- rel features: current + next register sets; load tile 0 now ----
    float rtc[4][4], rbc[4][4], rtn[4][4], rbn[4][4];
    {
        const int kk0 = half * NKT_HALF * 64;
#pragma unroll
        for (int r = 0; r < 4; ++r) {
            const size_t q = (size_t)(q0 + w16 + quad * 4 + r);
#pragma unroll
            for (int nt = 0; nt < 4; ++nt) {
                rtc[nt][r] = rtp[q * LQ + kk0 + nt * 16 + m];
                rbc[nt][r] = rbp[q * LQ + kk0 + nt * 16 + m];
            }
        }
    }

    // ---- stage Q (hi/lo) into the K buffers, load dqs (once per block) ----
    {
        const float* src = qp + ((size_t)(h * LQ + q0 + srow)) * DH + ss * 16;
        ushort8 vh0, vh1, vl0, vl1;
#pragma unroll
        for (int j = 0; j < 2; ++j) {
            float4 x = *(const float4*)(src + 4 * j);
            hl_t a = split2(x.x), b = split2(x.y), c = split2(x.z), d = split2(x.w);
            vh0[4*j+0]=a.h; vl0[4*j+0]=a.l; vh0[4*j+1]=b.h; vl0[4*j+1]=b.l;
            vh0[4*j+2]=c.h; vl0[4*j+2]=c.l; vh0[4*j+3]=d.h; vl0[4*j+3]=d.l;
        }
#pragma unroll
        for (int j = 0; j < 2; ++j) {
            float4 x = *(const float4*)(src + 8 + 4 * j);
            hl_t a = split2(x.x), b = split2(x.y), c = split2(x.z), d = split2(x.w);
            vh1[4*j+0]=a.h; vl1[4*j+0]=a.l; vh1[4*j+1]=b.h; vl1[4*j+1]=b.l;
            vh1[4*j+2]=c.h; vl1[4*j+2]=c.l; vh1[4*j+3]=d.h; vl1[4*j+3]=d.l;
        }
        *(ushort8*)&sh_khi[sbase] = vh0;  *(ushort8*)&sh_khi[sbase + 8] = vh1;
        *(ushort8*)&sh_klo[sbase] = vl0;  *(ushort8*)&sh_klo[sbase + 8] = vl1;
        if (t < 64) {
            sh_dqs[t * 3 + 0] = dqp[(q0 + t) * 3 + 0];
            sh_dqs[t * 3 + 1] = dqp[(q0 + t) * 3 + 1];
            sh_dqs[t * 3 + 2] = dqp[(q0 + t) * 3 + 2];
        }
    }
    __syncthreads();

    // Q A-fragments live in registers for the whole kernel
    bf16x8 aqh[2], aql[2];
#pragma unroll
    for (int kc = 0; kc < 2; ++kc) {
        aqh[kc] = *(const bf16x8*)&sh_khi[(w16 + m) * 72 + kc * 32 + quad * 8];
        aql[kc] = *(const bf16x8*)&sh_klo[(w16 + m) * 72 + kc * 32 + quad * 8];
    }
    float dq0[4], dq1[4], dq2[4];
#pragma unroll
    for (int r = 0; r < 4; ++r) {
        const int row = w16 + quad * 4 + r;
        dq0[r] = sh_dqs[row * 3 + 0]; dq1[r] = sh_dqs[row * 3 + 1]; dq2[r] = sh_dqs[row * 3 + 2];
    }
    __syncthreads();   // Q buffers free for K staging

    const floatx4 zf = {0.f, 0.f, 0.f, 0.f};
    floatx4 pacc[4] = {zf, zf, zf, zf};
    float lpart[4] = {0.f, 0.f, 0.f, 0.f};

    for (int kth = 0; kth < NKT_HALF; ++kth) {
        const int k0 = (half * NKT_HALF + kth) * 64;

        // ---- STAGE_WRITE: reg -> LDS (tile kth; loads were issued last iter) ----
        *(ushort8*)&sh_khi[sbase]     = rkh0;
        *(ushort8*)&sh_khi[sbase + 8] = rkh1;
        *(ushort8*)&sh_klo[sbase]     = rkl0;
        *(ushort8*)&sh_klo[sbase + 8] = rkl1;
        *(ushort8*)&sh_vhi[sbase]     = rvh0;
        *(ushort8*)&sh_vhi[sbase + 8] = rvh1;
        *(ushort8*)&sh_vlo[sbase]     = rvl0;
        *(ushort8*)&sh_vlo[sbase + 8] = rvl1;
        if (t < 192) *(float4*)&sh_meta[mk * 12 + mj * 4] = rmeta;
        __syncthreads();   // B1: tile kth resident in LDS

        // ---- STAGE_LOAD: issue tile kth+1 global loads (hide under compute) ----
        if (kth + 1 < NKT_HALF) {
            kgb += (size_t)64 * DH;
            vgb += (size_t)64 * 64;
            mgb += (size_t)64 * 12;
            rkh0 = *(const ushort8*)&khig[kgb];
            rkh1 = *(const ushort8*)&khig[kgb + 8];
            rkl0 = *(const ushort8*)&klog[kgb];
            rkl1 = *(const ushort8*)&klog[kgb + 8];
            rvh0 = *(const ushort8*)&vhig[vgb];
            rvh1 = *(const ushort8*)&vhig[vgb + 8];
            rvl0 = *(const ushort8*)&vlog[vgb];
            rvl1 = *(const ushort8*)&vlog[vgb + 8];
            if (t < 192) rmeta = *(const float4*)&metag[mgb];
            // rel features for tile kth+1 (consumed by next tile's epilogue)
            const int k1 = k0 + 64;
#pragma unroll
            for (int r = 0; r < 4; ++r) {
                const size_t q = (size_t)(q0 + w16 + quad * 4 + r);
#pragma unroll
                for (int nt = 0; nt < 4; ++nt) {
                    rtn[nt][r] = rtp[q * LQ + k1 + nt * 16 + m];
                    rbn[nt][r] = rbp[q * LQ + k1 + nt * 16 + m];
                }
            }
        }

        // ---- QK^T: 3-term split-bf16 MFMA (0.125 pre-folded into K) ----
        floatx4 sc[4] = {zf, zf, zf, zf};
#pragma unroll
        for (int nt = 0; nt < 4; ++nt) {
#pragma unroll
            for (int kc = 0; kc < 2; ++kc) {
                const int kb = (nt * 16 + m) * 72 + kc * 32 + quad * 8;
                bf16x8 bh = *(const bf16x8*)&sh_khi[kb];
                bf16x8 bl = *(const bf16x8*)&sh_klo[kb];
                sc[nt] = MFMA16(aqh[kc], bh, sc[nt]);
                sc[nt] = MFMA16(aql[kc], bh, sc[nt]);
                sc[nt] = MFMA16(aqh[kc], bl, sc[nt]);
            }
        }
        // no barrier here: ebf has its own buffer; PV reads only own-wave rows

        // ---- epilogue: gate + bias + exp; probs store; P->LDS ----
#pragma unroll
        for (int nt = 0; nt < 4; ++nt) {
            const int kcol = nt * 16 + m;
            const float m0 = sh_meta[kcol * 12 + 0],  m1 = sh_meta[kcol * 12 + 1];
            const float m2 = sh_meta[kcol * 12 + 2],  m3 = sh_meta[kcol * 12 + 3];
            const float m4 = sh_meta[kcol * 12 + 4],  m5 = sh_meta[kcol * 12 + 5];
            const float m6 = sh_meta[kcol * 12 + 6],  m7 = sh_meta[kcol * 12 + 7];
            const float m8 = sh_meta[kcol * 12 + 8],  m9 = sh_meta[kcol * 12 + 9];
            const float mA = sh_meta[kcol * 12 + 10], mB = sh_meta[kcol * 12 + 11];
#pragma unroll
            for (int r = 0; r < 4; ++r) {
                float ww = fmaf(dq0[r], m0, m3); ww = fmaf(dq1[r], m1, ww); ww = fmaf(dq2[r], m2, ww);
                ww = fmaf(rtc[nt][r], m8, ww);   ww = fmaf(rbc[nt][r], m9, ww);
                float bb = fmaf(dq0[r], m4, m7); bb = fmaf(dq1[r], m5, bb); bb = fmaf(dq2[r], m6, bb);
                bb = fmaf(rtc[nt][r], mA, bb);   bb = fmaf(rbc[nt][r], mB, bb);
                const float wg = fmaxf(ww, 0.f) + __logf(1.f + __expf(-fabsf(ww)));
                const float sv = fmaf(sc[nt][r], wg, bb);
                const float e  = __expf(sv - 8.0f);   // constant shift cancels in normalization
                lpart[r] += e;
                probp[((size_t)(h * LQ + q0 + w16 + quad * 4 + r)) * LQ + k0 + kcol] = e;
                sh_ebf[(w16 + quad * 4 + r) * 72 + kcol] = bf_rne(e);
            }
        }

        // ---- PV: bf16 P x split-bf16 V (own-wave rows; no barrier before reads) ----
        bf16x8 ap0 = *(const bf16x8*)&sh_ebf[(w16 + m) * 72 + quad * 8];
        bf16x8 ap1 = *(const bf16x8*)&sh_ebf[(w16 + m) * 72 + 32 + quad * 8];
#pragma unroll
        for (int nt = 0; nt < 4; ++nt) {
            const int vb = (nt * 16 + m) * 72 + quad * 8;
            bf16x8 bh0 = *(const bf16x8*)&sh_vhi[vb];
            bf16x8 bl0 = *(const bf16x8*)&sh_vlo[vb];
            bf16x8 bh1 = *(const bf16x8*)&sh_vhi[vb + 32];
            bf16x8 bl1 = *(const bf16x8*)&sh_vlo[vb + 32];
            pacc[nt] = MFMA16(ap0, bh0, pacc[nt]);
            pacc[nt] = MFMA16(ap0, bl0, pacc[nt]);
            pacc[nt] = MFMA16(ap1, bh1, pacc[nt]);
            pacc[nt] = MFMA16(ap1, bl1, pacc[nt]);
        }

        // ---- rotate rel double-buffer (loads issued a full phase ago) ----
        if (kth + 1 < NKT_HALF) {
#pragma unroll
            for (int r = 0; r < 4; ++r)
#pragma unroll
                for (int nt = 0; nt < 4; ++nt) {
                    rtc[nt][r] = rtn[nt][r];
                    rbc[nt][r] = rbn[nt][r];
                }
        }
        __syncthreads();   // B2: K/V/meta consumed; next iter overwrites LDS
    }

    // ---- row-sum partials: reduce over the 16 m-lanes ----
#pragma unroll
    for (int off = 1; off < 16; off <<= 1) {
#pragma unroll
        for (int r = 0; r < 4; ++r) lpart[r] += __shfl_xor(lpart[r], off, 64);
    }
    if (m == 0) {
#pragma unroll
        for (int r = 0; r < 4; ++r)
            lws[half * (NH * LQ) + h * LQ + q0 + w16 + quad * 4 + r] = lpart[r];
    }
    // ---- PV partials to ws ----
#pragma unroll
    for (int nt = 0; nt < 4; ++nt) {
#pragma unroll
        for (int r = 0; r < 4; ++r) {
            const size_t row = (size_t)(h * LQ + q0 + w16 + quad * 4 + r);
            pvws[(size_t)half * (NH * LQ * DH) + row * DH + nt * 16 + m] = pacc[nt][r];
        }
    }
}

// ---------------------------------------------------------------------------
// norm_combine: probs[row][k] = e * c[k] / l[row]  AND  out = (pv0+pv1)/l.
// 2048 blocks x 8 rows: c loaded once per block into regs (reused 8x).
// ---------------------------------------------------------------------------
__global__ __launch_bounds__(256) void norm_combine(
    float* __restrict__ probp, const float* __restrict__ cp,
    const float* __restrict__ lws, const float* __restrict__ pvws,
    float* __restrict__ outp)
{
    __shared__ float rl8[8];
    const int t    = threadIdx.x;
    const int row0 = blockIdx.x * 8;
    const float4 c0 = *(const float4*)(cp + t * 4);
    const float4 c1 = *(const float4*)(cp + (t + 256) * 4);
    if (t < 8) rl8[t] = 1.0f / (lws[row0 + t] + lws[NH * LQ + row0 + t]);
    __syncthreads();
#pragma unroll 2
    for (int rr = 0; rr < 8; ++rr) {
        const float rl = rl8[rr];
        float* p = probp + (size_t)(row0 + rr) * LQ;
        float4 x0 = *(const float4*)(p + t * 4);
        float4 x1 = *(const float4*)(p + (t + 256) * 4);
        x0.x *= rl * c0.x; x0.y *= rl * c0.y; x0.z *= rl * c0.z; x0.w *= rl * c0.w;
        x1.x *= rl * c1.x; x1.y *= rl * c1.y; x1.z *= rl * c1.z; x1.w *= rl * c1.w;
        *(float4*)(p + t * 4)         = x0;
        *(float4*)(p + (t + 256) * 4) = x1;
    }
    // combine: 8 rows x 64 d = 512 outputs, 2 per thread
#pragma unroll
    for (int j = 0; j < 2; ++j) {
        const int lin = j * 256 + t;
        const int rr  = lin >> 6, d = lin & 63;
        const size_t rowd = (size_t)(row0 + rr) * DH + d;
        outp[rowd] = (pvws[rowd] + pvws[(size_t)(NH * LQ * DH) + rowd]) * rl8[rr];
    }
}

extern "C" void kernel_launch(void* const* d_in, const int* in_sizes, int n_in,
                              void* d_out, int out_size, void* d_ws, size_t ws_size,
                              hipStream_t stream)
{
    (void)in_sizes; (void)n_in; (void)out_size; (void)ws_size;
    const float* qp   = (const float*)d_in[0];
    const float* kp   = (const float*)d_in[1];
    const float* vp   = (const float*)d_in[2];
    const float* cp   = (const float*)d_in[3];
    const float* dqp  = (const float*)d_in[4];
    const float* dktp = (const float*)d_in[5];
    const float* dkbp = (const float*)d_in[6];
    const float* dksp = (const float*)d_in[7];
    const float* rtp  = (const float*)d_in[8];
    const float* rbp  = (const float*)d_in[9];
    const float* Wwp  = (const float*)d_in[10];
    const float* Wbp  = (const float*)d_in[11];

    float* outp  = (float*)d_out;                            // [1,8,2048,64]
    float* probp = (float*)d_out + (size_t)NH * LQ * DH;     // [1,8,2048,2048]

    // Workspace layout (17.7 MB, proven sufficient by R4/R5 runs):
    //   lws   [2][NH*LQ]            f32
    //   pvws  [2][NH*LQ*DH]         f32
    //   khig/klog/vhig/vlog [NH*LQ*DH] bf16 each
    //   metag [NH*LQ*12]            f32
    float* lws  = (float*)d_ws;
    float* pvws = lws + 2 * (NH * LQ);
    unsigned short* khig = (unsigned short*)(pvws + (size_t)2 * NH * LQ * DH);
    unsigned short* klog = khig + (size_t)NH * LQ * DH;
    unsigned short* vhig = klog + (size_t)NH * LQ * DH;
    unsigned short* vlog = vhig + (size_t)NH * LQ * DH;
    float* metag = (float*)(vlog + (size_t)NH * LQ * DH);

    prep_kernel<<<dim3(576), dim3(256), 0, stream>>>(
        kp, vp, cp, dktp, dkbp, dksp, Wwp, Wbp, khig, klog, vhig, vlog, metag);
    attn_main<<<dim3(512), dim3(256), 0, stream>>>(
        qp, dqp, rtp, rbp, khig, klog, vhig, vlog, metag, probp, lws, pvws);
    norm_combine<<<dim3(2048), dim3(256), 0, stream>>>(probp, cp, lws, pvws, outp);
}